// Round 3
// baseline (663.058 us; speedup 1.0000x reference)
//
#include <hip/hip_runtime.h>
#include <stdint.h>

#define S_LEN 2048
#define EMB   2048
#define NHEAD 32
#define HDIM  64
#define QKVN  3072   // 2048 q + 512 k + 512 v
#define KOFF  2048
#define VOFF  2560

typedef __attribute__((ext_vector_type(8))) short short8;
typedef __attribute__((ext_vector_type(4))) short short4v;
typedef __attribute__((ext_vector_type(4))) float f32x4;

__device__ __forceinline__ unsigned short f2bf(float f) {
  union { float f; unsigned u; } v; v.f = f;
  return (unsigned short)((v.u + 0x7fffu + ((v.u >> 16) & 1u)) >> 16);
}

__device__ __forceinline__ f32x4 mfma16(short8 a, short8 b, f32x4 c) {
  return __builtin_amdgcn_mfma_f32_16x16x32_bf16(a, b, c, 0, 0, 0);
}

__device__ __forceinline__ void gload_lds16(const void* g, void* l) {
  __builtin_amdgcn_global_load_lds(
      (const __attribute__((address_space(1))) void*)g,
      (__attribute__((address_space(3))) void*)l, 16, 0, 0);
}

__device__ __forceinline__ unsigned cvt_pk_bf16(float lo, float hi) {
  unsigned r;
  asm("v_cvt_pk_bf16_f32 %0, %1, %2" : "=v"(r) : "v"(lo), "v"(hi));
  return r;
}

// ---------------- fused fp32 -> bf16 convert (all 5 tensors) ----------------
// regions (elems): x 4M | Wq 4M | Wk 1M | Wv 1M | Wo 4M ; one float4/thread
__global__ __launch_bounds__(256) void k_cvt_all(
    const float* __restrict__ x, const float* __restrict__ Wq,
    const float* __restrict__ Wk, const float* __restrict__ Wv,
    const float* __restrict__ Wo, unsigned short* __restrict__ xb,
    unsigned short* __restrict__ wqkv, unsigned short* __restrict__ wob) {
  long i = (long)(blockIdx.x * blockDim.x + threadIdx.x) * 4;
  const float* src; unsigned short* dst; long off;
  if (i < 4194304L)       { src = x;  dst = xb;             off = i; }
  else if (i < 8388608L)  { src = Wq; dst = wqkv;           off = i - 4194304L; }
  else if (i < 9437184L)  { src = Wk; dst = wqkv + 4194304; off = i - 8388608L; }
  else if (i < 10485760L) { src = Wv; dst = wqkv + 5242880; off = i - 9437184L; }
  else                    { src = Wo; dst = wob;            off = i - 10485760L; }
  float4 v = *reinterpret_cast<const float4*>(src + off);
  short4v o;
  o.x = (short)f2bf(v.x); o.y = (short)f2bf(v.y);
  o.z = (short)f2bf(v.z); o.w = (short)f2bf(v.w);
  *reinterpret_cast<short4v*>(dst + off) = o;
}

__global__ void k_bias_cat(const float* __restrict__ bq, const float* __restrict__ bk,
                           const float* __restrict__ bv, float* __restrict__ dst) {
  int i = blockIdx.x * blockDim.x + threadIdx.x;   // grid covers exactly 3072
  if (i < 2048) dst[i] = bq[i];
  else if (i < 2560) dst[i] = bk[i - 2048];
  else dst[i] = bv[i - 2560];
}

// ---------------- GEMM: C[M,N] = A[M,K] @ B[N,K]^T + bias ----------------
template <typename OUT_T>
__global__ __launch_bounds__(256) void k_gemm_bt(
    const unsigned short* __restrict__ A, const unsigned short* __restrict__ B,
    const float* __restrict__ bias, OUT_T* __restrict__ C, int M, int N, int K) {
  __shared__ unsigned short As[128 * 32];
  __shared__ unsigned short Bs[128 * 32];
  const int t = threadIdx.x;
  const int l = t & 63;
  const int w = t >> 6;
  const int m0 = blockIdx.x * 128;
  const int n0 = blockIdx.y * 128;
  const int wm = w >> 1, wn = w & 1;

  f32x4 acc[4][4] = {};

  const unsigned short* ga0 = A + (size_t)(m0 + (t >> 2)) * K + (t & 3) * 8;
  const unsigned short* ga1 = ga0 + (size_t)64 * K;
  const unsigned short* gb0 = B + (size_t)(n0 + (t >> 2)) * K + (t & 3) * 8;
  const unsigned short* gb1 = gb0 + (size_t)64 * K;
  unsigned short* la0 = As + t * 8;
  unsigned short* la1 = As + 2048 + t * 8;
  unsigned short* lb0 = Bs + t * 8;
  unsigned short* lb1 = Bs + 2048 + t * 8;

  const int lr = l & 15;
  const int lk = (l >> 4) * 8;
  const unsigned short* arow = As + (wm * 64 + lr) * 32 + lk;
  const unsigned short* brow = Bs + (wn * 64 + lr) * 32 + lk;

  for (int k0 = 0; k0 < K; k0 += 32) {
    gload_lds16(ga0, la0);
    gload_lds16(ga1, la1);
    gload_lds16(gb0, lb0);
    gload_lds16(gb1, lb1);
    ga0 += 32; ga1 += 32; gb0 += 32; gb1 += 32;
    __syncthreads();
    short8 af[4], bfv[4];
#pragma unroll
    for (int i = 0; i < 4; i++) {
      af[i]  = *reinterpret_cast<const short8*>(arow + i * 16 * 32);
      bfv[i] = *reinterpret_cast<const short8*>(brow + i * 16 * 32);
    }
#pragma unroll
    for (int i = 0; i < 4; i++)
#pragma unroll
      for (int j = 0; j < 4; j++)
        acc[i][j] = mfma16(af[i], bfv[j], acc[i][j]);
    __syncthreads();
  }

  const int lg = l >> 4;
#pragma unroll
  for (int i = 0; i < 4; i++) {
#pragma unroll
    for (int j = 0; j < 4; j++) {
      int col = n0 + wn * 64 + j * 16 + lr;
      float bb = bias[col];
#pragma unroll
      for (int r = 0; r < 4; r++) {
        int row = m0 + wm * 64 + i * 16 + lg * 4 + r;
        float val = acc[i][j][r] + bb;
        if constexpr (sizeof(OUT_T) == 2)
          C[(size_t)row * N + col] = (OUT_T)f2bf(val);
        else
          C[(size_t)row * N + col] = (OUT_T)val;
      }
    }
  }
}

// ---------------- V transpose: vT[gd][pos] = qkv[pos][VOFF+gd] ----------------
__global__ __launch_bounds__(256) void k_vT(const unsigned short* __restrict__ qkv,
                                            unsigned short* __restrict__ vT) {
  __shared__ unsigned short tile[64][72];
  const int t = threadIdx.x;
  const int p0 = (blockIdx.x & 31) * 64;
  const int g0 = (blockIdx.x >> 5) * 64;
  {
    const int pl = t >> 3;
    const int gl = (t & 7) * 8;
#pragma unroll
    for (int i = 0; i < 2; i++) {
      int p = pl + i * 32;
      short8 v = *reinterpret_cast<const short8*>(qkv + (size_t)(p0 + p) * QKVN + VOFF + g0 + gl);
#pragma unroll
      for (int j = 0; j < 8; j++) tile[p][gl + j] = (unsigned short)v[j];
    }
  }
  __syncthreads();
  {
    const int gr = t >> 3;
    const int pc = (t & 7) * 8;
#pragma unroll
    for (int i = 0; i < 2; i++) {
      int g = gr + i * 32;
      short8 o;
#pragma unroll
      for (int j = 0; j < 8; j++) o[j] = (short)tile[pc + j][g];
      *reinterpret_cast<short8*>(vT + (size_t)(g0 + g) * S_LEN + p0 + pc) = o;
    }
  }
}

// ---------------- fused attention v3 ----------------
// Block = 1 head x 16 q-rows, 512 threads (8 waves).
// Scores in registers (swapped QK^T, lane owns q-row l&15, wave owns 256-col
// stripe). Softmax in-register, one exp pass. Normalized P written straight
// to attn_w (plain stores -> L2 merges lines). PV re-reads P rows from L2
// with full-line f32x4 loads, packs to bf16 via v_cvt_pk_bf16_f32.
// PV split: wave = (hd-tile w&3, k-half w>>2); one f32x4 partial per lane;
// waves 4-7 park partials in 5KB LDS, waves 0-3 add + write hout.
__global__ __launch_bounds__(512, 4) void k_attn(
    const unsigned short* __restrict__ qkv, const unsigned short* __restrict__ vT,
    float* __restrict__ attn_w, unsigned short* __restrict__ hout) {
  __shared__ float red_mx[8 * 16];
  __shared__ float red_sm[8 * 16];
  __shared__ float pvredT[4][16][20];   // [hd-tile][hd-lane][16q + pad4]

  const int t = threadIdx.x;
  const int l = t & 63;
  const int w = t >> 6;               // 8 waves
  const int h = blockIdx.x >> 7;      // head
  const int r0 = (blockIdx.x & 127) * 16;
  const int g = h >> 2;               // kv group
  const int lr = l & 15;
  const int lg = l >> 4;              // 0..3
  const int lk = lg * 8;

  // Q fragment = B operand: col/q-row r0+lr, k = lk..lk+7 (+32 for 2nd half)
  const unsigned short* qbase = qkv + (size_t)(r0 + lr) * QKVN + h * HDIM + lk;
  const short8 bq0 = *reinterpret_cast<const short8*>(qbase);
  const short8 bq1 = *reinterpret_cast<const short8*>(qbase + 32);

  // ---- scores^T in regs: acc[i] covers cols w*256 + i*16 + lg*4 + {0..3} ----
  f32x4 acc[16];
  const unsigned short* kbase =
      qkv + (size_t)KOFF + g * HDIM + lk + (size_t)(w * 256 + lr) * QKVN;
#pragma unroll
  for (int i = 0; i < 16; i++) {
    const unsigned short* kp = kbase + (size_t)(i * 16) * QKVN;
    short8 a0 = *reinterpret_cast<const short8*>(kp);
    short8 a1 = *reinterpret_cast<const short8*>(kp + 32);
    f32x4 a = {};
    a = mfma16(a0, bq0, a);
    a = mfma16(a1, bq1, a);
    acc[i] = a * 0.125f;
  }

  // ---- row max (all of a lane's values belong to q-row r0+lr) ----
  float mx = -1e30f;
#pragma unroll
  for (int i = 0; i < 16; i++)
    mx = fmaxf(mx, fmaxf(fmaxf(acc[i][0], acc[i][1]), fmaxf(acc[i][2], acc[i][3])));
  mx = fmaxf(mx, __shfl_xor(mx, 16, 64));
  mx = fmaxf(mx, __shfl_xor(mx, 32, 64));
  if (l < 16) red_mx[w * 16 + l] = mx;
  __syncthreads();
  float bm = red_mx[lr];
#pragma unroll
  for (int j = 1; j < 8; j++) bm = fmaxf(bm, red_mx[j * 16 + lr]);

  // ---- single exp pass + row sum ----
  float sm = 0.f;
#pragma unroll
  for (int i = 0; i < 16; i++) {
#pragma unroll
    for (int r = 0; r < 4; r++) {
      float e = __expf(acc[i][r] - bm);
      acc[i][r] = e;
      sm += e;
    }
  }
  sm += __shfl_xor(sm, 16, 64);
  sm += __shfl_xor(sm, 32, 64);
  if (l < 16) red_sm[w * 16 + l] = sm;
  __syncthreads();
  float bs = 0.f;
#pragma unroll
  for (int j = 0; j < 8; j++) bs += red_sm[j * 16 + lr];
  const float inv = 1.0f / bs;

  // ---- normalize; plain f32x4 stores (L2 merges 64B halves into lines) ----
  float* aout = attn_w + (size_t)h * S_LEN * S_LEN + (size_t)(r0 + lr) * S_LEN + w * 256;
#pragma unroll
  for (int i = 0; i < 16; i++) {
    f32x4 p = acc[i] * inv;
    *reinterpret_cast<f32x4*>(aout + i * 16 + lg * 4) = p;
  }
  __syncthreads();   // drains stores (vmcnt 0) -> P visible in L2 for re-read

  // ---- PV: re-read P rows from L2; wave = (hd-tile, k-half) ----
  const int ht = w & 3;
  const int kh = w >> 2;
  const float* prow =
      attn_w + (size_t)h * S_LEN * S_LEN + (size_t)(r0 + lr) * S_LEN + kh * 1024;
  const unsigned short* vtb =
      vT + (size_t)(g * HDIM + ht * 16 + lr) * S_LEN + kh * 1024;
  f32x4 pv = {};
#pragma unroll 4
  for (int ii = 0; ii < 32; ii++) {
    const int k0 = ii * 32 + lk;
    f32x4 pa = *reinterpret_cast<const f32x4*>(prow + k0);
    f32x4 pb = *reinterpret_cast<const f32x4*>(prow + k0 + 4);
    union { short8 s; unsigned u[4]; } af;
    af.u[0] = cvt_pk_bf16(pa[0], pa[1]);
    af.u[1] = cvt_pk_bf16(pa[2], pa[3]);
    af.u[2] = cvt_pk_bf16(pb[0], pb[1]);
    af.u[3] = cvt_pk_bf16(pb[2], pb[3]);
    short8 vf = *reinterpret_cast<const short8*>(vtb + k0);
    pv = mfma16(af.s, vf, pv);
  }
  // lane holds out[q = lg*4+r][hd = ht*16+lr]
  if (w >= 4)
    *reinterpret_cast<f32x4*>(&pvredT[ht][lr][lg * 4]) = pv;
  __syncthreads();
  if (w < 4) {
    f32x4 o = pv + *reinterpret_cast<const f32x4*>(&pvredT[ht][lr][lg * 4]);
#pragma unroll
    for (int r = 0; r < 4; r++)
      hout[(size_t)(r0 + lg * 4 + r) * EMB + h * HDIM + ht * 16 + lr] = f2bf(o[r]);
  }
}

extern "C" void kernel_launch(void* const* d_in, const int* in_sizes, int n_in,
                              void* d_out, int out_size, void* d_ws, size_t ws_size,
                              hipStream_t stream) {
  const float* x  = (const float*)d_in[0];
  const float* Wq = (const float*)d_in[1];
  const float* bq = (const float*)d_in[2];
  const float* Wk = (const float*)d_in[3];
  const float* bk = (const float*)d_in[4];
  const float* Wv = (const float*)d_in[5];
  const float* bv = (const float*)d_in[6];
  const float* Wo = (const float*)d_in[7];
  const float* bo = (const float*)d_in[8];
  float* out = (float*)d_out;

  char* ws = (char*)d_ws;
  unsigned short* x_bf  = (unsigned short*)(ws);                 // 8 MiB
  unsigned short* wqkv  = (unsigned short*)(ws + (8ull  << 20)); // 12 MiB
  unsigned short* wo_bf = (unsigned short*)(ws + (20ull << 20)); // 8 MiB
  float*          bqkv  = (float*)         (ws + (28ull << 20)); // 12 KiB
  unsigned short* qkv   = (unsigned short*)(ws + (29ull << 20)); // 12 MiB
  unsigned short* vT    = (unsigned short*)(ws + (41ull << 20)); // 2 MiB
  unsigned short* hout  = (unsigned short*)(ws + (43ull << 20)); // 8 MiB

  k_cvt_all<<<14336, 256, 0, stream>>>(x, Wq, Wk, Wv, Wo, x_bf, wqkv, wo_bf);
  k_bias_cat<<<12, 256, 0, stream>>>(bq, bk, bv, bqkv);

  dim3 g1(16, 24);  // M/128 x N/128
  k_gemm_bt<unsigned short><<<g1, 256, 0, stream>>>(x_bf, wqkv, bqkv, qkv, 2048, 3072, 2048);
  k_vT<<<256, 256, 0, stream>>>(qkv, vT);
  k_attn<<<4096, 512, 0, stream>>>(qkv, vT, out, hout);
  dim3 g2(16, 16);
  k_gemm_bt<float><<<g2, 256, 0, stream>>>(hout, wo_bf, bo, out + (size_t)NHEAD * S_LEN * S_LEN, 2048, 2048, 2048);
}

// Round 5
// 530.379 us; speedup vs baseline: 1.2502x; 1.2502x over previous
//
#include <hip/hip_runtime.h>
#include <stdint.h>

#define S_LEN 2048
#define EMB   2048
#define NHEAD 32
#define HDIM  64
#define QKVN  3072   // 2048 q + 512 k + 512 v
#define KOFF  2048
#define VOFF  2560

typedef __attribute__((ext_vector_type(8))) short short8;
typedef __attribute__((ext_vector_type(4))) short short4v;
typedef __attribute__((ext_vector_type(4))) float f32x4;
typedef __attribute__((ext_vector_type(2))) float f32x2;

__device__ __forceinline__ unsigned short f2bf(float f) {
  union { float f; unsigned u; } v; v.f = f;
  return (unsigned short)((v.u + 0x7fffu + ((v.u >> 16) & 1u)) >> 16);
}

__device__ __forceinline__ f32x4 mfma16(short8 a, short8 b, f32x4 c) {
  return __builtin_amdgcn_mfma_f32_16x16x32_bf16(a, b, c, 0, 0, 0);
}

__device__ __forceinline__ void gload_lds16(const void* g, void* l) {
  __builtin_amdgcn_global_load_lds(
      (const __attribute__((address_space(1))) void*)g,
      (__attribute__((address_space(3))) void*)l, 16, 0, 0);
}

__device__ __forceinline__ unsigned cvt_pk_bf16(float lo, float hi) {
  unsigned r;
  asm("v_cvt_pk_bf16_f32 %0, %1, %2" : "=v"(r) : "v"(lo), "v"(hi));
  return r;
}

// ---------------- fused fp32 -> bf16 convert (all 5 tensors) ----------------
__global__ __launch_bounds__(256) void k_cvt_all(
    const float* __restrict__ x, const float* __restrict__ Wq,
    const float* __restrict__ Wk, const float* __restrict__ Wv,
    const float* __restrict__ Wo, unsigned short* __restrict__ xb,
    unsigned short* __restrict__ wqkv, unsigned short* __restrict__ wob) {
  long i = (long)(blockIdx.x * blockDim.x + threadIdx.x) * 4;
  const float* src; unsigned short* dst; long off;
  if (i < 4194304L)       { src = x;  dst = xb;             off = i; }
  else if (i < 8388608L)  { src = Wq; dst = wqkv;           off = i - 4194304L; }
  else if (i < 9437184L)  { src = Wk; dst = wqkv + 4194304; off = i - 8388608L; }
  else if (i < 10485760L) { src = Wv; dst = wqkv + 5242880; off = i - 9437184L; }
  else                    { src = Wo; dst = wob;            off = i - 10485760L; }
  float4 v = *reinterpret_cast<const float4*>(src + off);
  short4v o;
  o.x = (short)f2bf(v.x); o.y = (short)f2bf(v.y);
  o.z = (short)f2bf(v.z); o.w = (short)f2bf(v.w);
  *reinterpret_cast<short4v*>(dst + off) = o;
}

__global__ void k_bias_cat(const float* __restrict__ bq, const float* __restrict__ bk,
                           const float* __restrict__ bv, float* __restrict__ dst) {
  int i = blockIdx.x * blockDim.x + threadIdx.x;   // grid covers exactly 3072
  if (i < 2048) dst[i] = bq[i];
  else if (i < 2560) dst[i] = bk[i - 2048];
  else dst[i] = bv[i - 2560];
}

// ---------------- GEMM: C[M,N] = A[M,K] @ B[N,K]^T + bias ----------------
template <typename OUT_T>
__global__ __launch_bounds__(256) void k_gemm_bt(
    const unsigned short* __restrict__ A, const unsigned short* __restrict__ B,
    const float* __restrict__ bias, OUT_T* __restrict__ C, int M, int N, int K) {
  __shared__ unsigned short As[128 * 32];
  __shared__ unsigned short Bs[128 * 32];
  const int t = threadIdx.x;
  const int l = t & 63;
  const int w = t >> 6;
  const int m0 = blockIdx.x * 128;
  const int n0 = blockIdx.y * 128;
  const int wm = w >> 1, wn = w & 1;

  f32x4 acc[4][4] = {};

  const unsigned short* ga0 = A + (size_t)(m0 + (t >> 2)) * K + (t & 3) * 8;
  const unsigned short* ga1 = ga0 + (size_t)64 * K;
  const unsigned short* gb0 = B + (size_t)(n0 + (t >> 2)) * K + (t & 3) * 8;
  const unsigned short* gb1 = gb0 + (size_t)64 * K;
  unsigned short* la0 = As + t * 8;
  unsigned short* la1 = As + 2048 + t * 8;
  unsigned short* lb0 = Bs + t * 8;
  unsigned short* lb1 = Bs + 2048 + t * 8;

  const int lr = l & 15;
  const int lk = (l >> 4) * 8;
  const unsigned short* arow = As + (wm * 64 + lr) * 32 + lk;
  const unsigned short* brow = Bs + (wn * 64 + lr) * 32 + lk;

  for (int k0 = 0; k0 < K; k0 += 32) {
    gload_lds16(ga0, la0);
    gload_lds16(ga1, la1);
    gload_lds16(gb0, lb0);
    gload_lds16(gb1, lb1);
    ga0 += 32; ga1 += 32; gb0 += 32; gb1 += 32;
    __syncthreads();
    short8 af[4], bfv[4];
#pragma unroll
    for (int i = 0; i < 4; i++) {
      af[i]  = *reinterpret_cast<const short8*>(arow + i * 16 * 32);
      bfv[i] = *reinterpret_cast<const short8*>(brow + i * 16 * 32);
    }
#pragma unroll
    for (int i = 0; i < 4; i++)
#pragma unroll
      for (int j = 0; j < 4; j++)
        acc[i][j] = mfma16(af[i], bfv[j], acc[i][j]);
    __syncthreads();
  }

  const int lg = l >> 4;
#pragma unroll
  for (int i = 0; i < 4; i++) {
#pragma unroll
    for (int j = 0; j < 4; j++) {
      int col = n0 + wn * 64 + j * 16 + lr;
      float bb = bias[col];
#pragma unroll
      for (int r = 0; r < 4; r++) {
        int row = m0 + wm * 64 + i * 16 + lg * 4 + r;
        float val = acc[i][j][r] + bb;
        if constexpr (sizeof(OUT_T) == 2)
          C[(size_t)row * N + col] = (OUT_T)f2bf(val);
        else
          C[(size_t)row * N + col] = (OUT_T)val;
      }
    }
  }
}

// ---------------- V transpose: vT[gd][pos] = qkv[pos][VOFF+gd] ----------------
__global__ __launch_bounds__(256) void k_vT(const unsigned short* __restrict__ qkv,
                                            unsigned short* __restrict__ vT) {
  __shared__ unsigned short tile[64][72];
  const int t = threadIdx.x;
  const int p0 = (blockIdx.x & 31) * 64;
  const int g0 = (blockIdx.x >> 5) * 64;
  {
    const int pl = t >> 3;
    const int gl = (t & 7) * 8;
#pragma unroll
    for (int i = 0; i < 2; i++) {
      int p = pl + i * 32;
      short8 v = *reinterpret_cast<const short8*>(qkv + (size_t)(p0 + p) * QKVN + VOFF + g0 + gl);
#pragma unroll
      for (int j = 0; j < 8; j++) tile[p][gl + j] = (unsigned short)v[j];
    }
  }
  __syncthreads();
  {
    const int gr = t >> 3;
    const int pc = (t & 7) * 8;
#pragma unroll
    for (int i = 0; i < 2; i++) {
      int g = gr + i * 32;
      short8 o;
#pragma unroll
      for (int j = 0; j < 8; j++) o[j] = (short)tile[pc + j][g];
      *reinterpret_cast<short8*>(vT + (size_t)(g0 + g) * S_LEN + p0 + pc) = o;
    }
  }
}

// ---------------- fused attention v5: P in registers, PV via 16x16x32 ------
// Block = 1 head x 16 q-rows, 512 threads (8 waves); wave w owns k-stripe
// [w*256, w*256+256). Swapped QK^T: lane(lr,lg) holds P[q=lr][k=i*16+lg*4+{0..3}].
// PV uses the SAME verified 16x16x32 MFMA: its k-slot kappa = lg*8+j is a
// bijective relabeling, so define source col c(kappa): j<4 -> chunk 2s col
// lg*4+j; j>=4 -> chunk 2s+1 col 16+lg*4+(j-4). A-frag = concat of two P
// chunks (registers we already hold); B-frag = two 8B vT loads with the same
// permutation. D: lane(lr,lg) reg r = out[q=lg*4+r][hd=ht*16+lr].
// Cross-wave reduce via pvred LDS, one barrier, 2 outputs/thread.
__global__ __launch_bounds__(512, 4) void k_attn(
    const unsigned short* __restrict__ qkv, const unsigned short* __restrict__ vT,
    float* __restrict__ attn_w, unsigned short* __restrict__ hout) {
  __shared__ float red_mx[8 * 16];
  __shared__ float red_sm[8 * 16];
  __shared__ float pvred[8][16][68];    // [wave][q][hd] + pad

  const int t = threadIdx.x;
  const int l = t & 63;
  const int w = t >> 6;               // 8 waves
  const int h = blockIdx.x >> 7;      // head
  const int r0 = (blockIdx.x & 127) * 16;
  const int g = h >> 2;               // kv group
  const int lr = l & 15;
  const int lg = l >> 4;              // 0..3
  const int lk = lg * 8;

  // Q fragment = B operand of QK^T: col/q-row r0+lr, k = lk..lk+7 (+32)
  const unsigned short* qbase = qkv + (size_t)(r0 + lr) * QKVN + h * HDIM + lk;
  const short8 bq0 = *reinterpret_cast<const short8*>(qbase);
  const short8 bq1 = *reinterpret_cast<const short8*>(qbase + 32);

  // ---- scores^T in regs: acc[i] = P-chunk, cols w*256 + i*16 + lg*4 + {0..3} ----
  f32x4 acc[16];
  const unsigned short* kbase =
      qkv + (size_t)KOFF + g * HDIM + lk + (size_t)(w * 256 + lr) * QKVN;
#pragma unroll
  for (int i = 0; i < 16; i++) {
    const unsigned short* kp = kbase + (size_t)(i * 16) * QKVN;
    short8 a0 = *reinterpret_cast<const short8*>(kp);
    short8 a1 = *reinterpret_cast<const short8*>(kp + 32);
    f32x4 a = {};
    a = mfma16(a0, bq0, a);
    a = mfma16(a1, bq1, a);
    acc[i] = a * 0.125f;
  }

  // ---- row max (all of a lane's values belong to q-row r0+lr) ----
  float mx = -1e30f;
#pragma unroll
  for (int i = 0; i < 16; i++)
    mx = fmaxf(mx, fmaxf(fmaxf(acc[i][0], acc[i][1]), fmaxf(acc[i][2], acc[i][3])));
  mx = fmaxf(mx, __shfl_xor(mx, 16, 64));
  mx = fmaxf(mx, __shfl_xor(mx, 32, 64));
  if (l < 16) red_mx[w * 16 + l] = mx;
  __syncthreads();
  float bm = red_mx[lr];
#pragma unroll
  for (int j = 1; j < 8; j++) bm = fmaxf(bm, red_mx[j * 16 + lr]);

  // ---- single exp pass + row sum ----
  float sm = 0.f;
#pragma unroll
  for (int i = 0; i < 16; i++) {
#pragma unroll
    for (int r = 0; r < 4; r++) {
      float e = __expf(acc[i][r] - bm);
      acc[i][r] = e;
      sm += e;
    }
  }
  sm += __shfl_xor(sm, 16, 64);
  sm += __shfl_xor(sm, 32, 64);
  if (l < 16) red_sm[w * 16 + l] = sm;
  __syncthreads();
  float bs = 0.f;
#pragma unroll
  for (int j = 0; j < 8; j++) bs += red_sm[j * 16 + lr];
  const float inv = 1.0f / bs;

  // ---- normalize; store attn_w (plain f32x4, L2 merges); pack A-frags ----
  // pa8[s] = concat(bf16(chunk 2s), bf16(chunk 2s+1)) -> 16x16x32 A operand
  float* aout = attn_w + (size_t)h * S_LEN * S_LEN + (size_t)(r0 + lr) * S_LEN + w * 256;
  union A8 { short8 s; unsigned u[4]; } pa8[8];
#pragma unroll
  for (int i = 0; i < 16; i++) {
    f32x4 p = acc[i] * inv;
    *reinterpret_cast<f32x4*>(aout + i * 16 + lg * 4) = p;
    pa8[i >> 1].u[(i & 1) * 2 + 0] = cvt_pk_bf16(p[0], p[1]);
    pa8[i >> 1].u[(i & 1) * 2 + 1] = cvt_pk_bf16(p[2], p[3]);
  }

  // ---- PV from registers: wave's own 256-k stripe, all 4 hd-tiles ----
  // B-frag(ht,s): j<4 from vT[hd][w*256+s*32+lg*4+j], j>=4 from +16
  const unsigned short* vtb =
      vT + (size_t)(g * HDIM + lr) * S_LEN + w * 256 + lg * 4;
  const unsigned short* vtb1 = vtb + (size_t)16 * S_LEN;
  const unsigned short* vtb2 = vtb + (size_t)32 * S_LEN;
  const unsigned short* vtb3 = vtb + (size_t)48 * S_LEN;
  f32x4 pv0 = {}, pv1 = {}, pv2 = {}, pv3 = {};
#pragma unroll
  for (int s = 0; s < 8; s++) {
    const int base = s * 32;
    union A8 b0, b1, b2, b3;
    *reinterpret_cast<short4v*>(&b0.u[0]) = *reinterpret_cast<const short4v*>(vtb  + base);
    *reinterpret_cast<short4v*>(&b0.u[2]) = *reinterpret_cast<const short4v*>(vtb  + base + 16);
    *reinterpret_cast<short4v*>(&b1.u[0]) = *reinterpret_cast<const short4v*>(vtb1 + base);
    *reinterpret_cast<short4v*>(&b1.u[2]) = *reinterpret_cast<const short4v*>(vtb1 + base + 16);
    *reinterpret_cast<short4v*>(&b2.u[0]) = *reinterpret_cast<const short4v*>(vtb2 + base);
    *reinterpret_cast<short4v*>(&b2.u[2]) = *reinterpret_cast<const short4v*>(vtb2 + base + 16);
    *reinterpret_cast<short4v*>(&b3.u[0]) = *reinterpret_cast<const short4v*>(vtb3 + base);
    *reinterpret_cast<short4v*>(&b3.u[2]) = *reinterpret_cast<const short4v*>(vtb3 + base + 16);
    pv0 = mfma16(pa8[s].s, b0.s, pv0);
    pv1 = mfma16(pa8[s].s, b1.s, pv1);
    pv2 = mfma16(pa8[s].s, b2.s, pv2);
    pv3 = mfma16(pa8[s].s, b3.s, pv3);
  }
  // lane holds out_partial[q = lg*4+r][hd = ht*16+lr]
#pragma unroll
  for (int r = 0; r < 4; r++) {
    pvred[w][lg * 4 + r][lr]      = pv0[r];
    pvred[w][lg * 4 + r][16 + lr] = pv1[r];
    pvred[w][lg * 4 + r][32 + lr] = pv2[r];
    pvred[w][lg * 4 + r][48 + lr] = pv3[r];
  }
  __syncthreads();

  // ---- cross-wave reduce + hout write: 2 outputs per thread ----
  {
    const int q = t >> 5;
    const int hd = (t & 31) * 2;
    float s0 = 0.f, s1 = 0.f;
#pragma unroll
    for (int s = 0; s < 8; s++) {
      f32x2 v = *reinterpret_cast<const f32x2*>(&pvred[s][q][hd]);
      s0 += v.x; s1 += v.y;
    }
    union { unsigned u; unsigned short s[2]; } o;
    o.s[0] = f2bf(s0); o.s[1] = f2bf(s1);
    *reinterpret_cast<unsigned*>(
        &hout[(size_t)(r0 + q) * EMB + h * HDIM + hd]) = o.u;
  }
}

extern "C" void kernel_launch(void* const* d_in, const int* in_sizes, int n_in,
                              void* d_out, int out_size, void* d_ws, size_t ws_size,
                              hipStream_t stream) {
  const float* x  = (const float*)d_in[0];
  const float* Wq = (const float*)d_in[1];
  const float* bq = (const float*)d_in[2];
  const float* Wk = (const float*)d_in[3];
  const float* bk = (const float*)d_in[4];
  const float* Wv = (const float*)d_in[5];
  const float* bv = (const float*)d_in[6];
  const float* Wo = (const float*)d_in[7];
  const float* bo = (const float*)d_in[8];
  float* out = (float*)d_out;

  char* ws = (char*)d_ws;
  unsigned short* x_bf  = (unsigned short*)(ws);                 // 8 MiB
  unsigned short* wqkv  = (unsigned short*)(ws + (8ull  << 20)); // 12 MiB
  unsigned short* wo_bf = (unsigned short*)(ws + (20ull << 20)); // 8 MiB
  float*          bqkv  = (float*)         (ws + (28ull << 20)); // 12 KiB
  unsigned short* qkv   = (unsigned short*)(ws + (29ull << 20)); // 12 MiB
  unsigned short* vT    = (unsigned short*)(ws + (41ull << 20)); // 2 MiB
  unsigned short* hout  = (unsigned short*)(ws + (43ull << 20)); // 8 MiB

  k_cvt_all<<<14336, 256, 0, stream>>>(x, Wq, Wk, Wv, Wo, x_bf, wqkv, wo_bf);
  k_bias_cat<<<12, 256, 0, stream>>>(bq, bk, bv, bqkv);

  dim3 g1(16, 24);  // M/128 x N/128
  k_gemm_bt<unsigned short><<<g1, 256, 0, stream>>>(x_bf, wqkv, bqkv, qkv, 2048, 3072, 2048);
  k_vT<<<256, 256, 0, stream>>>(qkv, vT);
  k_attn<<<4096, 512, 0, stream>>>(qkv, vT, out, hout);
  dim3 g2(16, 16);
  k_gemm_bt<float><<<g2, 256, 0, stream>>>(hout, wo_bf, bo, out + (size_t)NHEAD * S_LEN * S_LEN, 2048, 2048, 2048);
}

// Round 6
// 496.113 us; speedup vs baseline: 1.3365x; 1.0691x over previous
//
#include <hip/hip_runtime.h>
#include <stdint.h>

#define S_LEN 2048
#define EMB   2048
#define NHEAD 32
#define HDIM  64
#define QKVN  3072   // 2048 q + 512 k + 512 v
#define KOFF  2048
#define VOFF  2560

typedef __attribute__((ext_vector_type(8))) short short8;
typedef __attribute__((ext_vector_type(4))) short short4v;
typedef __attribute__((ext_vector_type(4))) float f32x4;
typedef __attribute__((ext_vector_type(2))) float f32x2;

__device__ __forceinline__ unsigned short f2bf(float f) {
  union { float f; unsigned u; } v; v.f = f;
  return (unsigned short)((v.u + 0x7fffu + ((v.u >> 16) & 1u)) >> 16);
}

__device__ __forceinline__ f32x4 mfma16(short8 a, short8 b, f32x4 c) {
  return __builtin_amdgcn_mfma_f32_16x16x32_bf16(a, b, c, 0, 0, 0);
}

__device__ __forceinline__ void gload_lds16(const void* g, void* l) {
  __builtin_amdgcn_global_load_lds(
      (const __attribute__((address_space(1))) void*)g,
      (__attribute__((address_space(3))) void*)l, 16, 0, 0);
}

__device__ __forceinline__ unsigned cvt_pk_bf16(float lo, float hi) {
  unsigned r;
  asm("v_cvt_pk_bf16_f32 %0, %1, %2" : "=v"(r) : "v"(lo), "v"(hi));
  return r;
}

__device__ __forceinline__ float bperm_f32(int idx_bytes, float v) {
  int r = __builtin_amdgcn_ds_bpermute(idx_bytes, __builtin_bit_cast(int, v));
  return __builtin_bit_cast(float, r);
}

// ---------------- fused fp32 -> bf16 convert (all 5 tensors) ----------------
__global__ __launch_bounds__(256) void k_cvt_all(
    const float* __restrict__ x, const float* __restrict__ Wq,
    const float* __restrict__ Wk, const float* __restrict__ Wv,
    const float* __restrict__ Wo, unsigned short* __restrict__ xb,
    unsigned short* __restrict__ wqkv, unsigned short* __restrict__ wob) {
  long i = (long)(blockIdx.x * blockDim.x + threadIdx.x) * 4;
  const float* src; unsigned short* dst; long off;
  if (i < 4194304L)       { src = x;  dst = xb;             off = i; }
  else if (i < 8388608L)  { src = Wq; dst = wqkv;           off = i - 4194304L; }
  else if (i < 9437184L)  { src = Wk; dst = wqkv + 4194304; off = i - 8388608L; }
  else if (i < 10485760L) { src = Wv; dst = wqkv + 5242880; off = i - 9437184L; }
  else                    { src = Wo; dst = wob;            off = i - 10485760L; }
  float4 v = *reinterpret_cast<const float4*>(src + off);
  short4v o;
  o.x = (short)f2bf(v.x); o.y = (short)f2bf(v.y);
  o.z = (short)f2bf(v.z); o.w = (short)f2bf(v.w);
  *reinterpret_cast<short4v*>(dst + off) = o;
}

__global__ void k_bias_cat(const float* __restrict__ bq, const float* __restrict__ bk,
                           const float* __restrict__ bv, float* __restrict__ dst) {
  int i = blockIdx.x * blockDim.x + threadIdx.x;   // grid covers exactly 3072
  if (i < 2048) dst[i] = bq[i];
  else if (i < 2560) dst[i] = bk[i - 2048];
  else dst[i] = bv[i - 2560];
}

// ---------------- GEMM: C[M,N] = A[M,K] @ B[N,K]^T + bias ----------------
template <typename OUT_T>
__global__ __launch_bounds__(256) void k_gemm_bt(
    const unsigned short* __restrict__ A, const unsigned short* __restrict__ B,
    const float* __restrict__ bias, OUT_T* __restrict__ C, int M, int N, int K) {
  __shared__ unsigned short As[128 * 32];
  __shared__ unsigned short Bs[128 * 32];
  const int t = threadIdx.x;
  const int l = t & 63;
  const int w = t >> 6;
  const int m0 = blockIdx.x * 128;
  const int n0 = blockIdx.y * 128;
  const int wm = w >> 1, wn = w & 1;

  f32x4 acc[4][4] = {};

  const unsigned short* ga0 = A + (size_t)(m0 + (t >> 2)) * K + (t & 3) * 8;
  const unsigned short* ga1 = ga0 + (size_t)64 * K;
  const unsigned short* gb0 = B + (size_t)(n0 + (t >> 2)) * K + (t & 3) * 8;
  const unsigned short* gb1 = gb0 + (size_t)64 * K;
  unsigned short* la0 = As + t * 8;
  unsigned short* la1 = As + 2048 + t * 8;
  unsigned short* lb0 = Bs + t * 8;
  unsigned short* lb1 = Bs + 2048 + t * 8;

  const int lr = l & 15;
  const int lk = (l >> 4) * 8;
  const unsigned short* arow = As + (wm * 64 + lr) * 32 + lk;
  const unsigned short* brow = Bs + (wn * 64 + lr) * 32 + lk;

  for (int k0 = 0; k0 < K; k0 += 32) {
    gload_lds16(ga0, la0);
    gload_lds16(ga1, la1);
    gload_lds16(gb0, lb0);
    gload_lds16(gb1, lb1);
    ga0 += 32; ga1 += 32; gb0 += 32; gb1 += 32;
    __syncthreads();
    short8 af[4], bfv[4];
#pragma unroll
    for (int i = 0; i < 4; i++) {
      af[i]  = *reinterpret_cast<const short8*>(arow + i * 16 * 32);
      bfv[i] = *reinterpret_cast<const short8*>(brow + i * 16 * 32);
    }
#pragma unroll
    for (int i = 0; i < 4; i++)
#pragma unroll
      for (int j = 0; j < 4; j++)
        acc[i][j] = mfma16(af[i], bfv[j], acc[i][j]);
    __syncthreads();
  }

  const int lg = l >> 4;
#pragma unroll
  for (int i = 0; i < 4; i++) {
#pragma unroll
    for (int j = 0; j < 4; j++) {
      int col = n0 + wn * 64 + j * 16 + lr;
      float bb = bias[col];
#pragma unroll
      for (int r = 0; r < 4; r++) {
        int row = m0 + wm * 64 + i * 16 + lg * 4 + r;
        float val = acc[i][j][r] + bb;
        if constexpr (sizeof(OUT_T) == 2)
          C[(size_t)row * N + col] = (OUT_T)f2bf(val);
        else
          C[(size_t)row * N + col] = (OUT_T)val;
      }
    }
  }
}

// ---------------- V transpose: vT[gd][pos] = qkv[pos][VOFF+gd] ----------------
__global__ __launch_bounds__(256) void k_vT(const unsigned short* __restrict__ qkv,
                                            unsigned short* __restrict__ vT) {
  __shared__ unsigned short tile[64][72];
  const int t = threadIdx.x;
  const int p0 = (blockIdx.x & 31) * 64;
  const int g0 = (blockIdx.x >> 5) * 64;
  {
    const int pl = t >> 3;
    const int gl = (t & 7) * 8;
#pragma unroll
    for (int i = 0; i < 2; i++) {
      int p = pl + i * 32;
      short8 v = *reinterpret_cast<const short8*>(qkv + (size_t)(p0 + p) * QKVN + VOFF + g0 + gl);
#pragma unroll
      for (int j = 0; j < 8; j++) tile[p][gl + j] = (unsigned short)v[j];
    }
  }
  __syncthreads();
  {
    const int gr = t >> 3;
    const int pc = (t & 7) * 8;
#pragma unroll
    for (int i = 0; i < 2; i++) {
      int g = gr + i * 32;
      short8 o;
#pragma unroll
      for (int j = 0; j < 8; j++) o[j] = (short)tile[pc + j][g];
      *reinterpret_cast<short8*>(vT + (size_t)(g0 + g) * S_LEN + p0 + pc) = o;
    }
  }
}

// ---------------- fused attention v6: full-line nt stores via bpermute ------
// Same as v5 (P in registers, PV via 16x16x32 relabeling) except the attn_w
// store phase: in-wave ds_bpermute repack so each store instruction writes
// 8 rows x 128B full aligned lines (the fillBuffer pattern), nontemporal.
// dest lane l (row=l>>3 within half, j=l&7): pulls col-quad j of its row from
// source lane (j&3)*16 + row_abs; X-chunk (acc[2s]) for j<4, Y (acc[2s+1])
// for j>=4. Final barrier is lgkmcnt-only so the pvred reduce doesn't wait
// for the global store drain.
__global__ __launch_bounds__(512, 4) void k_attn(
    const unsigned short* __restrict__ qkv, const unsigned short* __restrict__ vT,
    float* __restrict__ attn_w, unsigned short* __restrict__ hout) {
  __shared__ float red_mx[8 * 16];
  __shared__ float red_sm[8 * 16];
  __shared__ float pvred[8][16][68];    // [wave][q][hd] + pad

  const int t = threadIdx.x;
  const int l = t & 63;
  const int w = t >> 6;               // 8 waves
  const int h = blockIdx.x >> 7;      // head
  const int r0 = (blockIdx.x & 127) * 16;
  const int g = h >> 2;               // kv group
  const int lr = l & 15;
  const int lg = l >> 4;              // 0..3
  const int lk = lg * 8;

  // Q fragment = B operand of QK^T: col/q-row r0+lr, k = lk..lk+7 (+32)
  const unsigned short* qbase = qkv + (size_t)(r0 + lr) * QKVN + h * HDIM + lk;
  const short8 bq0 = *reinterpret_cast<const short8*>(qbase);
  const short8 bq1 = *reinterpret_cast<const short8*>(qbase + 32);

  // ---- scores^T in regs: acc[i] = P-chunk, cols w*256 + i*16 + lg*4 + {0..3} ----
  f32x4 acc[16];
  const unsigned short* kbase =
      qkv + (size_t)KOFF + g * HDIM + lk + (size_t)(w * 256 + lr) * QKVN;
#pragma unroll
  for (int i = 0; i < 16; i++) {
    const unsigned short* kp = kbase + (size_t)(i * 16) * QKVN;
    short8 a0 = *reinterpret_cast<const short8*>(kp);
    short8 a1 = *reinterpret_cast<const short8*>(kp + 32);
    f32x4 a = {};
    a = mfma16(a0, bq0, a);
    a = mfma16(a1, bq1, a);
    acc[i] = a * 0.125f;
  }

  // ---- row max (all of a lane's values belong to q-row r0+lr) ----
  float mx = -1e30f;
#pragma unroll
  for (int i = 0; i < 16; i++)
    mx = fmaxf(mx, fmaxf(fmaxf(acc[i][0], acc[i][1]), fmaxf(acc[i][2], acc[i][3])));
  mx = fmaxf(mx, __shfl_xor(mx, 16, 64));
  mx = fmaxf(mx, __shfl_xor(mx, 32, 64));
  if (l < 16) red_mx[w * 16 + l] = mx;
  __syncthreads();
  float bm = red_mx[lr];
#pragma unroll
  for (int j = 1; j < 8; j++) bm = fmaxf(bm, red_mx[j * 16 + lr]);

  // ---- single exp pass + row sum ----
  float sm = 0.f;
#pragma unroll
  for (int i = 0; i < 16; i++) {
#pragma unroll
    for (int r = 0; r < 4; r++) {
      float e = __expf(acc[i][r] - bm);
      acc[i][r] = e;
      sm += e;
    }
  }
  sm += __shfl_xor(sm, 16, 64);
  sm += __shfl_xor(sm, 32, 64);
  if (l < 16) red_sm[w * 16 + l] = sm;
  __syncthreads();
  float bs = 0.f;
#pragma unroll
  for (int j = 0; j < 8; j++) bs += red_sm[j * 16 + lr];
  const float inv = 1.0f / bs;

  // ---- normalize in place + pack bf16 A-frags for PV ----
  union A8 { short8 s; unsigned u[4]; } pa8[8];
#pragma unroll
  for (int i = 0; i < 16; i++) {
    acc[i] *= inv;
    pa8[i >> 1].u[(i & 1) * 2 + 0] = cvt_pk_bf16(acc[i][0], acc[i][1]);
    pa8[i >> 1].u[(i & 1) * 2 + 1] = cvt_pk_bf16(acc[i][2], acc[i][3]);
  }

  // ---- attn_w store: bpermute repack -> 8 rows x 128B full lines, nt ----
  {
    const int jj = l & 7;              // col-quad within 32-col line
    const int rown = l >> 3;           // row within 8-row half
    const int idx0 = ((l & 3) * 16 + rown) * 4;   // source lane (h=0), bytes
    const int idx1 = idx0 + 32;                   // +8 rows for h=1
    const bool hiq = (l & 4) != 0;
    float* b0 = attn_w + (size_t)h * S_LEN * S_LEN
              + (size_t)(r0 + rown) * S_LEN + w * 256 + jj * 4;
    float* b1 = b0 + 8 * S_LEN;
#pragma unroll
    for (int s = 0; s < 8; s++) {
      f32x4 X = acc[2 * s], Y = acc[2 * s + 1];
      f32x4 o0, o1;
#pragma unroll
      for (int c = 0; c < 4; c++) {
        float x0 = bperm_f32(idx0, X[c]);
        float y0 = bperm_f32(idx0, Y[c]);
        o0[c] = hiq ? y0 : x0;
        float x1 = bperm_f32(idx1, X[c]);
        float y1 = bperm_f32(idx1, Y[c]);
        o1[c] = hiq ? y1 : x1;
      }
      __builtin_nontemporal_store(o0, reinterpret_cast<f32x4*>(b0 + s * 32));
      __builtin_nontemporal_store(o1, reinterpret_cast<f32x4*>(b1 + s * 32));
    }
  }

  // ---- PV from registers: wave's own 256-k stripe, all 4 hd-tiles ----
  const unsigned short* vtb =
      vT + (size_t)(g * HDIM + lr) * S_LEN + w * 256 + lg * 4;
  const unsigned short* vtb1 = vtb + (size_t)16 * S_LEN;
  const unsigned short* vtb2 = vtb + (size_t)32 * S_LEN;
  const unsigned short* vtb3 = vtb + (size_t)48 * S_LEN;
  f32x4 pv0 = {}, pv1 = {}, pv2 = {}, pv3 = {};
#pragma unroll
  for (int s = 0; s < 8; s++) {
    const int base = s * 32;
    union A8 b0, b1, b2, b3;
    *reinterpret_cast<short4v*>(&b0.u[0]) = *reinterpret_cast<const short4v*>(vtb  + base);
    *reinterpret_cast<short4v*>(&b0.u[2]) = *reinterpret_cast<const short4v*>(vtb  + base + 16);
    *reinterpret_cast<short4v*>(&b1.u[0]) = *reinterpret_cast<const short4v*>(vtb1 + base);
    *reinterpret_cast<short4v*>(&b1.u[2]) = *reinterpret_cast<const short4v*>(vtb1 + base + 16);
    *reinterpret_cast<short4v*>(&b2.u[0]) = *reinterpret_cast<const short4v*>(vtb2 + base);
    *reinterpret_cast<short4v*>(&b2.u[2]) = *reinterpret_cast<const short4v*>(vtb2 + base + 16);
    *reinterpret_cast<short4v*>(&b3.u[0]) = *reinterpret_cast<const short4v*>(vtb3 + base);
    *reinterpret_cast<short4v*>(&b3.u[2]) = *reinterpret_cast<const short4v*>(vtb3 + base + 16);
    pv0 = mfma16(pa8[s].s, b0.s, pv0);
    pv1 = mfma16(pa8[s].s, b1.s, pv1);
    pv2 = mfma16(pa8[s].s, b2.s, pv2);
    pv3 = mfma16(pa8[s].s, b3.s, pv3);
  }
  // lane holds out_partial[q = lg*4+r][hd = ht*16+lr]
#pragma unroll
  for (int r = 0; r < 4; r++) {
    pvred[w][lg * 4 + r][lr]      = pv0[r];
    pvred[w][lg * 4 + r][16 + lr] = pv1[r];
    pvred[w][lg * 4 + r][32 + lr] = pv2[r];
    pvred[w][lg * 4 + r][48 + lr] = pv3[r];
  }
  // lgkmcnt-only barrier: don't wait for the nt store drain here
  asm volatile("s_waitcnt lgkmcnt(0)\n\ts_barrier" ::: "memory");
  __builtin_amdgcn_sched_barrier(0);

  // ---- cross-wave reduce + hout write: 2 outputs per thread ----
  {
    const int q = t >> 5;
    const int hd = (t & 31) * 2;
    float s0 = 0.f, s1 = 0.f;
#pragma unroll
    for (int s = 0; s < 8; s++) {
      f32x2 v = *reinterpret_cast<const f32x2*>(&pvred[s][q][hd]);
      s0 += v.x; s1 += v.y;
    }
    union { unsigned u; unsigned short s[2]; } o;
    o.s[0] = f2bf(s0); o.s[1] = f2bf(s1);
    *reinterpret_cast<unsigned*>(
        &hout[(size_t)(r0 + q) * EMB + h * HDIM + hd]) = o.u;
  }
}

extern "C" void kernel_launch(void* const* d_in, const int* in_sizes, int n_in,
                              void* d_out, int out_size, void* d_ws, size_t ws_size,
                              hipStream_t stream) {
  const float* x  = (const float*)d_in[0];
  const float* Wq = (const float*)d_in[1];
  const float* bq = (const float*)d_in[2];
  const float* Wk = (const float*)d_in[3];
  const float* bk = (const float*)d_in[4];
  const float* Wv = (const float*)d_in[5];
  const float* bv = (const float*)d_in[6];
  const float* Wo = (const float*)d_in[7];
  const float* bo = (const float*)d_in[8];
  float* out = (float*)d_out;

  char* ws = (char*)d_ws;
  unsigned short* x_bf  = (unsigned short*)(ws);                 // 8 MiB
  unsigned short* wqkv  = (unsigned short*)(ws + (8ull  << 20)); // 12 MiB
  unsigned short* wo_bf = (unsigned short*)(ws + (20ull << 20)); // 8 MiB
  float*          bqkv  = (float*)         (ws + (28ull << 20)); // 12 KiB
  unsigned short* qkv   = (unsigned short*)(ws + (29ull << 20)); // 12 MiB
  unsigned short* vT    = (unsigned short*)(ws + (41ull << 20)); // 2 MiB
  unsigned short* hout  = (unsigned short*)(ws + (43ull << 20)); // 8 MiB

  k_cvt_all<<<14336, 256, 0, stream>>>(x, Wq, Wk, Wv, Wo, x_bf, wqkv, wo_bf);
  k_bias_cat<<<12, 256, 0, stream>>>(bq, bk, bv, bqkv);

  dim3 g1(16, 24);  // M/128 x N/128
  k_gemm_bt<unsigned short><<<g1, 256, 0, stream>>>(x_bf, wqkv, bqkv, qkv, 2048, 3072, 2048);
  k_vT<<<256, 256, 0, stream>>>(qkv, vT);
  k_attn<<<4096, 512, 0, stream>>>(qkv, vT, out, hout);
  dim3 g2(16, 16);
  k_gemm_bt<float><<<g2, 256, 0, stream>>>(hout, wo_bf, bo, out + (size_t)NHEAD * S_LEN * S_LEN, 2048, 2048, 2048);
}